// Round 3
// baseline (229.076 us; speedup 1.0000x reference)
//
#include <hip/hip_runtime.h>
#include <hip/hip_bf16.h>

typedef __attribute__((ext_vector_type(8))) short short8;
typedef __attribute__((ext_vector_type(4))) float f32x4;

#define BB 2
#define LL 2048
#define DD 1024
#define HH 16
#define DHH 64
#define KK 1024
#define VST 80   // padded LDS row stride (shorts): 160 B, 16B-aligned

__device__ __forceinline__ void gload_lds16(const void* g, void* l) {
  __builtin_amdgcn_global_load_lds((const __attribute__((address_space(1))) void*)g,
                                   (__attribute__((address_space(3))) void*)l,
                                   16, 0, 0);
}

__device__ __forceinline__ f32x4 splat4(float x) {
  f32x4 v; v[0] = x; v[1] = x; v[2] = x; v[3] = x; return v;
}

__device__ __forceinline__ unsigned short f2b(float x) {
  __hip_bfloat16 h = __float2bfloat16(x);
  return *reinterpret_cast<unsigned short*>(&h);
}

// fp32 -> bf16 bulk convert, 8 elements/thread
__global__ void cvt_f32_bf16(const float* __restrict__ src,
                             __hip_bfloat16* __restrict__ dst, int n8) {
  int i = blockIdx.x * blockDim.x + threadIdx.x;
  if (i >= n8) return;
  const f32x4 a = ((const f32x4*)src)[i * 2];
  const f32x4 b = ((const f32x4*)src)[i * 2 + 1];
  short8 o;
#pragma unroll
  for (int j = 0; j < 4; ++j) o[j] = (short)f2b(a[j]);
#pragma unroll
  for (int j = 0; j < 4; ++j) o[4 + j] = (short)f2b(b[j]);
  ((short8*)dst)[i] = o;
}

// C = A @ B^T (+bias). A: MxK bf16 row-major, B: NxK bf16 row-major. K=1024.
// QKV mode scatters into per-head (B,H,L,DH) Q/K/V bf16 buffers with fp32 bias.
// Direct mode writes fp32 C[m*N+n].
template<bool QKV>
__global__ void gemm_bt(const __hip_bfloat16* __restrict__ A,
                        const __hip_bfloat16* __restrict__ Bm,
                        const float* __restrict__ bias,
                        __hip_bfloat16* __restrict__ Cq,
                        __hip_bfloat16* __restrict__ Ck,
                        __hip_bfloat16* __restrict__ Cv,
                        float* __restrict__ Cd,
                        int N, int nbn) {
  __shared__ __align__(16) char As[8192];
  __shared__ __align__(16) char Bs[8192];
  const int tid = threadIdx.x;
  const int lane = tid & 63, wid = tid >> 6;
  const int l15 = lane & 15, lhi = lane >> 4;
  const int wm = wid >> 1, wn = wid & 1;
  const int bn = blockIdx.x % nbn, bm = blockIdx.x / nbn;
  const int m0 = bm * 128, n0 = bn * 128;

  f32x4 acc[4][4] = {};

  for (int kt = 0; kt < KK / 32; ++kt) {
    const int k0 = kt * 32;
    __syncthreads();
    // stage A tile: LDS linear dest, source byte-chunk pre-swizzled
    // swizzle: byte ^= ((row>>1)&3)<<4  (within the 64B row)
#pragma unroll
    for (int j = 0; j < 2; ++j) {
      int c = wid * 128 + j * 64 + lane;       // 16B chunk index, lane-contig
      int row = c >> 2;
      int ab = ((c & 3) * 16) ^ (((row >> 1) & 3) << 4);
      gload_lds16(A + (size_t)(m0 + row) * KK + k0 + (ab >> 1),
                  As + wid * 2048 + j * 1024);
    }
#pragma unroll
    for (int j = 0; j < 2; ++j) {
      int c = wid * 128 + j * 64 + lane;
      int row = c >> 2;
      int ab = ((c & 3) * 16) ^ (((row >> 1) & 3) << 4);
      gload_lds16(Bm + (size_t)(n0 + row) * KK + k0 + (ab >> 1),
                  Bs + wid * 2048 + j * 1024);
    }
    __syncthreads();

    short8 af[4], bf[4];
#pragma unroll
    for (int mf = 0; mf < 4; ++mf) {
      int row = wm * 64 + mf * 16 + l15;
      int byt = (lhi * 16) ^ (((row >> 1) & 3) << 4);
      af[mf] = *(const short8*)(As + row * 64 + byt);
    }
#pragma unroll
    for (int nf = 0; nf < 4; ++nf) {
      int row = wn * 64 + nf * 16 + l15;
      int byt = (lhi * 16) ^ (((row >> 1) & 3) << 4);
      bf[nf] = *(const short8*)(Bs + row * 64 + byt);
    }
#pragma unroll
    for (int mf = 0; mf < 4; ++mf)
#pragma unroll
      for (int nf = 0; nf < 4; ++nf)
        acc[mf][nf] = __builtin_amdgcn_mfma_f32_16x16x32_bf16(af[mf], bf[nf],
                                                              acc[mf][nf], 0, 0, 0);
  }

  // epilogue: C/D layout col=lane&15, row=(lane>>4)*4+reg
#pragma unroll
  for (int mf = 0; mf < 4; ++mf) {
#pragma unroll
    for (int nf = 0; nf < 4; ++nf) {
      const int n = n0 + wn * 64 + nf * 16 + l15;
      if constexpr (QKV) {
        const int sect = n >> 10;          // 0=q 1=k 2=v
        const int nn = n & 1023;
        const int h = nn >> 6, dh = nn & 63;
        __hip_bfloat16* dst = (sect == 0) ? Cq : ((sect == 1) ? Ck : Cv);
        const float bv = bias[n];
#pragma unroll
        for (int r = 0; r < 4; ++r) {
          const int m = m0 + wm * 64 + mf * 16 + lhi * 4 + r;
          const int b = m >> 11, ml = m & 2047;
          dst[(((size_t)(b * HH + h)) * LL + ml) * DHH + dh] =
              __float2bfloat16(acc[mf][nf][r] + bv);
        }
      } else {
#pragma unroll
        for (int r = 0; r < 4; ++r) {
          const int m = m0 + wm * 64 + mf * 16 + lhi * 4 + r;
          Cd[(size_t)m * N + n] = acc[mf][nf][r];
        }
      }
    }
  }
}

// Flash attention: block = 128 q rows (4 waves x 32), KV tiles of 64, DH=64.
__global__ void attn_fwd(const __hip_bfloat16* __restrict__ Q,
                         const __hip_bfloat16* __restrict__ K,
                         const __hip_bfloat16* __restrict__ V,
                         __hip_bfloat16* __restrict__ att,
                         const int* __restrict__ maskp) {
  __shared__ __align__(16) char Ks[8192];                  // [64 kv][128B] swizzled
  __shared__ __align__(16) short Vs[64][VST];              // transposed [dh][kv]
  __shared__ __align__(16) __hip_bfloat16 Ps[4][32][VST];  // per-wave P
  const int tid = threadIdx.x;
  const int lane = tid & 63, wid = tid >> 6;
  const int l15 = lane & 15, lhi = lane >> 4;
  const int bid = blockIdx.x;
  const int qt = 15 - (bid >> 5);   // heavy q-tiles first
  const int bh = bid & 31;
  const int causal = *maskp;
  const __hip_bfloat16* Qg = Q + (size_t)bh * LL * DHH;
  const __hip_bfloat16* Kg = K + (size_t)bh * LL * DHH;
  const __hip_bfloat16* Vg = V + (size_t)bh * LL * DHH;
  const int r0 = qt * 128 + wid * 32;

  // Q fragments held in registers for the whole block
  short8 aq[2][2];
#pragma unroll
  for (int mf = 0; mf < 2; ++mf)
#pragma unroll
    for (int ks = 0; ks < 2; ++ks)
      aq[mf][ks] = *(const short8*)(Qg + (size_t)(r0 + mf * 16 + l15) * DHH +
                                    ks * 32 + lhi * 8);

  f32x4 o[2][4] = {};
  f32x4 mrun[2], lrun[2];
  mrun[0] = splat4(-1e30f); mrun[1] = splat4(-1e30f);
  lrun[0] = splat4(0.0f);   lrun[1] = splat4(0.0f);

  const int ntiles = causal ? (qt + 1) * 2 : (LL / 64);
  for (int t = 0; t < ntiles; ++t) {
    const int kv0 = t * 64;
    __syncthreads();
    // stage K tile, swizzled source: byte ^= (kv&7)<<4 within 128B row
#pragma unroll
    for (int j = 0; j < 2; ++j) {
      int c = wid * 128 + j * 64 + lane;
      int kv = c >> 3;
      int ab = ((c & 7) * 16) ^ ((kv & 7) << 4);
      gload_lds16(Kg + (size_t)(kv0 + kv) * DHH + (ab >> 1),
                  Ks + wid * 2048 + j * 1024);
    }
    // stage V transposed (reg round-trip, scalar LDS writes)
    {
      const int kvv = tid >> 2, dhb = (tid & 3) * 16;
      const __hip_bfloat16* src = Vg + (size_t)(kv0 + kvv) * DHH + dhb;
      short8 v0 = *(const short8*)src;
      short8 v1 = *(const short8*)(src + 8);
#pragma unroll
      for (int j = 0; j < 8; ++j) Vs[dhb + j][kvv] = v0[j];
#pragma unroll
      for (int j = 0; j < 8; ++j) Vs[dhb + 8 + j][kvv] = v1[j];
    }
    __syncthreads();

    if (!causal || kv0 <= r0 + 31) {
      // QK^T
      short8 bk[4][2];
#pragma unroll
      for (int nf = 0; nf < 4; ++nf) {
        int kv = nf * 16 + l15;
#pragma unroll
        for (int ks = 0; ks < 2; ++ks) {
          int byt = (ks * 64 + lhi * 16) ^ ((kv & 7) << 4);
          bk[nf][ks] = *(const short8*)(Ks + kv * 128 + byt);
        }
      }
      f32x4 s[2][4] = {};
#pragma unroll
      for (int mf = 0; mf < 2; ++mf)
#pragma unroll
        for (int nf = 0; nf < 4; ++nf) {
          s[mf][nf] = __builtin_amdgcn_mfma_f32_16x16x32_bf16(aq[mf][0], bk[nf][0], s[mf][nf], 0, 0, 0);
          s[mf][nf] = __builtin_amdgcn_mfma_f32_16x16x32_bf16(aq[mf][1], bk[nf][1], s[mf][nf], 0, 0, 0);
        }
      // scale + causal mask
      const bool needmask = causal && (kv0 + 63 > r0);
#pragma unroll
      for (int mf = 0; mf < 2; ++mf)
#pragma unroll
        for (int nf = 0; nf < 4; ++nf) {
          const int kv = kv0 + nf * 16 + l15;
#pragma unroll
          for (int r = 0; r < 4; ++r) {
            float v = s[mf][nf][r] * 0.125f;   // 1/sqrt(64)
            if (needmask && kv > r0 + mf * 16 + lhi * 4 + r) v = -1e30f;
            s[mf][nf][r] = v;
          }
        }
      // row max (reduce over nf, then 16-lane group)
#pragma unroll
      for (int mf = 0; mf < 2; ++mf) {
        f32x4 pm = s[mf][0];
#pragma unroll
        for (int nf = 1; nf < 4; ++nf)
#pragma unroll
          for (int r = 0; r < 4; ++r) pm[r] = fmaxf(pm[r], s[mf][nf][r]);
#pragma unroll
        for (int d = 1; d < 16; d <<= 1)
#pragma unroll
          for (int r = 0; r < 4; ++r) pm[r] = fmaxf(pm[r], __shfl_xor(pm[r], d, 64));

        f32x4 mnew, rsum;
#pragma unroll
        for (int r = 0; r < 4; ++r) {
          mnew[r] = fmaxf(mrun[mf][r], pm[r]);
          float sc = __expf(mrun[mf][r] - mnew[r]);
          lrun[mf][r] *= sc;
          rsum[r] = 0.0f;
#pragma unroll
          for (int nf = 0; nf < 4; ++nf) o[mf][nf][r] *= sc;
        }
#pragma unroll
        for (int nf = 0; nf < 4; ++nf)
#pragma unroll
          for (int r = 0; r < 4; ++r) {
            float p = __expf(s[mf][nf][r] - mnew[r]);
            s[mf][nf][r] = p;
            rsum[r] += p;
          }
#pragma unroll
        for (int d = 1; d < 16; d <<= 1)
#pragma unroll
          for (int r = 0; r < 4; ++r) rsum[r] += __shfl_xor(rsum[r], d, 64);
#pragma unroll
        for (int r = 0; r < 4; ++r) lrun[mf][r] += rsum[r];
        mrun[mf] = mnew;
      }
      // P -> LDS (layout change for PV A-operand)
#pragma unroll
      for (int mf = 0; mf < 2; ++mf)
#pragma unroll
        for (int nf = 0; nf < 4; ++nf)
#pragma unroll
          for (int r = 0; r < 4; ++r)
            Ps[wid][mf * 16 + lhi * 4 + r][nf * 16 + l15] =
                __float2bfloat16(s[mf][nf][r]);
      // PV
      short8 ap[2][2];
#pragma unroll
      for (int mf = 0; mf < 2; ++mf)
#pragma unroll
        for (int ks = 0; ks < 2; ++ks)
          ap[mf][ks] = *(const short8*)(&Ps[wid][mf * 16 + l15][ks * 32 + lhi * 8]);
      short8 bvf[4][2];
#pragma unroll
      for (int nf = 0; nf < 4; ++nf)
#pragma unroll
        for (int ks = 0; ks < 2; ++ks)
          bvf[nf][ks] = *(const short8*)(&Vs[nf * 16 + l15][ks * 32 + lhi * 8]);
#pragma unroll
      for (int mf = 0; mf < 2; ++mf)
#pragma unroll
        for (int nf = 0; nf < 4; ++nf) {
          o[mf][nf] = __builtin_amdgcn_mfma_f32_16x16x32_bf16(ap[mf][0], bvf[nf][0], o[mf][nf], 0, 0, 0);
          o[mf][nf] = __builtin_amdgcn_mfma_f32_16x16x32_bf16(ap[mf][1], bvf[nf][1], o[mf][nf], 0, 0, 0);
        }
    }
  }

  // finalize: att layout (B, L, H*DH) merged heads
  const int b = bh >> 4, h = bh & 15;
#pragma unroll
  for (int mf = 0; mf < 2; ++mf)
#pragma unroll
    for (int r = 0; r < 4; ++r) {
      const int row = r0 + mf * 16 + lhi * 4 + r;
      const float inv = 1.0f / lrun[mf][r];
#pragma unroll
      for (int nf = 0; nf < 4; ++nf)
        att[((size_t)(b * LL + row)) * DD + h * DHH + nf * 16 + l15] =
            __float2bfloat16(o[mf][nf][r] * inv);
    }
}

extern "C" void kernel_launch(void* const* d_in, const int* in_sizes, int n_in,
                              void* d_out, int out_size, void* d_ws, size_t ws_size,
                              hipStream_t stream) {
  const float* x     = (const float*)d_in[0];
  const float* w_in  = (const float*)d_in[1];
  const float* b_in  = (const float*)d_in[2];
  const float* w_out = (const float*)d_in[3];
  const int* mask    = (const int*)d_in[4];
  float* out = (float*)d_out;

  char* ws = (char*)d_ws;
  const size_t MiB = 1024u * 1024u;
  __hip_bfloat16* xb    = (__hip_bfloat16*)(ws);             // 8 MiB
  __hip_bfloat16* w_inb = (__hip_bfloat16*)(ws + 8 * MiB);   // 6 MiB
  __hip_bfloat16* w_outb= (__hip_bfloat16*)(ws + 14 * MiB);  // 2 MiB
  __hip_bfloat16* Qb    = (__hip_bfloat16*)(ws + 16 * MiB);  // 8 MiB
  __hip_bfloat16* Kb    = (__hip_bfloat16*)(ws + 24 * MiB);  // 8 MiB
  __hip_bfloat16* Vb    = (__hip_bfloat16*)(ws + 32 * MiB);  // 8 MiB
  __hip_bfloat16* att   = (__hip_bfloat16*)(ws + 40 * MiB);  // 8 MiB

  // fp32 -> bf16 conversions
  cvt_f32_bf16<<<dim3((BB * LL * DD) / 8 / 256), dim3(256), 0, stream>>>(x, xb, (BB * LL * DD) / 8);
  cvt_f32_bf16<<<dim3((3 * DD * DD) / 8 / 256), dim3(256), 0, stream>>>(w_in, w_inb, (3 * DD * DD) / 8);
  cvt_f32_bf16<<<dim3((DD * DD) / 8 / 256), dim3(256), 0, stream>>>(w_out, w_outb, (DD * DD) / 8);

  // QKV projection: (4096x1024) @ (3072x1024)^T + b_in, scatter to heads
  gemm_bt<true><<<dim3(32 * 24), dim3(256), 0, stream>>>(
      xb, w_inb, b_in, Qb, Kb, Vb, nullptr, 3072, 24);
  // attention
  attn_fwd<<<dim3(512), dim3(256), 0, stream>>>(Qb, Kb, Vb, att, mask);
  // output projection: (4096x1024) @ (1024x1024)^T -> fp32 out
  gemm_bt<false><<<dim3(32 * 8), dim3(256), 0, stream>>>(
      att, w_outb, nullptr, nullptr, nullptr, nullptr, out, 1024, 8);
}